// Round 1
// baseline (522.984 us; speedup 1.0000x reference)
//
#include <hip/hip_runtime.h>

#define VB 0.22360679774997896f  // 20^-0.5

// ---------------------------------------------------------------------------
// Stage 1: 256 patch experts. One block per patch p, 512 threads.
// GEMM per site: feat[128 x 96] @ W[96 x 400] done in 2 u-chunks (N=200),
// M chunk kept in LDS, chain matvec fused, BN stats block-local, BN folded
// into (sc1, sh1) applied by stage 2 on read. z1 holds RAW y.
// ---------------------------------------------------------------------------
__global__ __launch_bounds__(512, 2)
void stage1_kernel(const float* __restrict__ x,
                   const float* __restrict__ cores1,
                   const float* __restrict__ label1,
                   const float* __restrict__ g1,
                   const float* __restrict__ b1,
                   float* __restrict__ z1,
                   float* __restrict__ sc1,
                   float* __restrict__ sh1)
{
    // 158.7 KB static LDS (gfx950 allows up to 160 KiB/workgroup)
    __shared__ __align__(16) float xS[128 * 49];     // x values, padded row 49
    __shared__ __align__(16) float wS[16 * 320];     // W f-tile, per-tv padded to 40
    __shared__ __align__(16) float mS[128 * 201];    // M chunk [b][200], padded 201
    __shared__ __align__(16) float leftS[128 * 20];  // chain state
    __shared__ float redS[2];

    const int tid = threadIdx.x;
    const int bid = blockIdx.x;
    // XCD swizzle: consecutive p share x cache lines -> keep them on one XCD
    const int p = (bid & 7) * 32 + (bid >> 3);

    const int ph   = p >> 7;
    const int pw   = (p >> 6) & 1;
    const int irow = (p >> 2) & 15;
    const int jblk = p & 3;
    const int hh   = ph * 16 + irow;

    const int tv = tid & 7;    // 25 uv columns each
    const int tb = tid >> 3;   // 0..63 ; handles b = tb, tb+64
    const int mb = tid >> 2;   // matvec: 0..127
    const int mh = tid & 3;    // matvec: 5 v each

    for (int idx = tid; idx < 128 * 20; idx += 512) leftS[idx] = VB;

    #pragma unroll 1
    for (int n = 0; n < 4; ++n) {
        const int ww = pw * 16 + jblk * 4 + n;
        __syncthreads();
        // stage x pixel column (all b, all 48 channels) for this site
        for (int idx = tid; idx < 128 * 48; idx += 512) {
            int b = idx / 48;
            int c = idx - b * 48;
            xS[b * 49 + c] = x[((b * 48 + c) << 10) + hh * 32 + ww];
        }
        float lacc[5];
        #pragma unroll
        for (int j = 0; j < 5; ++j) lacc[j] = 0.f;

        const float* wpn = cores1 + (size_t)(p * 4 + n) * 38400;

        #pragma unroll 1
        for (int uc = 0; uc < 2; ++uc) {
            float acc0[25], acc1[25];
            #pragma unroll
            for (int j = 0; j < 25; ++j) { acc0[j] = 0.f; acc1[j] = 0.f; }
            const float* wbase = wpn + uc * 10 * 1920;

            #pragma unroll 1
            for (int ft = 0; ft < 6; ++ft) {
                __syncthreads();  // wS reusable (also orders xS writes 1st iter)
                for (int idx = tid; idx < 3200; idx += 512) {
                    int fi = idx / 200;
                    int c  = idx - fi * 200;       // true local uv
                    int ul = c / 20;
                    int vv = c - ul * 20;
                    int tw = c / 25;
                    int jj = c - tw * 25;
                    wS[fi * 320 + tw * 40 + jj] =
                        wbase[(ul * 96 + ft * 16 + fi) * 20 + vv];
                }
                __syncthreads();
                #pragma unroll
                for (int fi = 0; fi < 16; ++fi) {
                    const int f  = ft * 16 + fi;
                    const int cc = (ft >= 3) ? (f - 48) : f;
                    float a0 = xS[tb * 49 + cc];
                    float a1 = xS[(tb + 64) * 49 + cc];
                    if (ft >= 3) { a0 = 1.f - a0; a1 = 1.f - a1; }
                    float wv[25];
                    #pragma unroll
                    for (int g = 0; g < 6; ++g) {
                        float4 t = *reinterpret_cast<const float4*>(
                            &wS[fi * 320 + tv * 40 + 4 * g]);
                        wv[4*g+0] = t.x; wv[4*g+1] = t.y;
                        wv[4*g+2] = t.z; wv[4*g+3] = t.w;
                    }
                    wv[24] = wS[fi * 320 + tv * 40 + 24];
                    #pragma unroll
                    for (int j = 0; j < 25; ++j) {
                        acc0[j] += a0 * wv[j];
                        acc1[j] += a1 * wv[j];
                    }
                }
            }
            #pragma unroll
            for (int j = 0; j < 25; ++j) {
                mS[tb * 201 + tv * 25 + j]        = acc0[j];
                mS[(tb + 64) * 201 + tv * 25 + j] = acc1[j];
            }
            __syncthreads();
            // partial matvec over this u-chunk (rows uc*10 .. uc*10+9)
            #pragma unroll
            for (int ul = 0; ul < 10; ++ul) {
                float lv = leftS[mb * 20 + uc * 10 + ul];
                #pragma unroll
                for (int j = 0; j < 5; ++j)
                    lacc[j] += lv * mS[mb * 201 + ul * 20 + mh * 5 + j];
            }
        }
        __syncthreads();  // all leftS reads done
        #pragma unroll
        for (int j = 0; j < 5; ++j) leftS[mb * 20 + mh * 5 + j] = lacc[j];
    }
    __syncthreads();

    // label contraction: labv[u][o] = VB * sum_v label1[p][u][o][v]  (into wS)
    if (tid == 0) { redS[0] = 0.f; redS[1] = 0.f; }
    for (int idx = tid; idx < 400; idx += 512) {
        int u = idx / 20;
        int o = idx - u * 20;
        const float* lb = label1 + (size_t)((p * 20 + u) * 20 + o) * 20;
        float s = 0.f;
        #pragma unroll
        for (int vv = 0; vv < 20; ++vv) s += lb[vv];
        wS[idx] = s * VB;
    }
    __syncthreads();

    float yv[5];
    #pragma unroll
    for (int j = 0; j < 5; ++j) yv[j] = 0.f;
    #pragma unroll
    for (int u = 0; u < 20; ++u) {
        float lv = leftS[mb * 20 + u];
        #pragma unroll
        for (int j = 0; j < 5; ++j) yv[j] += lv * wS[u * 20 + mh * 5 + j];
    }
    float s = 0.f, s2 = 0.f;
    #pragma unroll
    for (int j = 0; j < 5; ++j) {
        z1[(size_t)mb * 5120 + p * 20 + mh * 5 + j] = yv[j];
        s += yv[j]; s2 += yv[j] * yv[j];
    }
    #pragma unroll
    for (int off = 32; off > 0; off >>= 1) {
        s  += __shfl_down(s, off);
        s2 += __shfl_down(s2, off);
    }
    if ((tid & 63) == 0) { atomicAdd(&redS[0], s); atomicAdd(&redS[1], s2); }
    __syncthreads();
    if (tid == 0) {
        float mean = redS[0] * (1.f / 2560.f);
        float var  = redS[1] * (1.f / 2560.f) - mean * mean;
        float rstd = rsqrtf(var + 1e-5f);
        float sc   = g1[p] * rstd;
        sc1[p] = sc;
        sh1[p] = b1[p] - mean * sc;
    }
}

// ---------------------------------------------------------------------------
// Stages 2 & 3 (templated): P experts, F=40, B-chunk 64, full N=400 GEMM.
// STAGE==2: affine from (sc1, sh1). STAGE==3: affine computed from stage-2
// global sums. Outputs raw y + atomic partial sums for its own BN.
// ---------------------------------------------------------------------------
template <int STAGE>
__global__ __launch_bounds__(512, 2)
void stageN_kernel(const float* __restrict__ zin,
                   const float* __restrict__ cores,
                   const float* __restrict__ label,
                   const float* __restrict__ scd,
                   const float* __restrict__ shd,
                   const float* __restrict__ gsin,
                   const float* __restrict__ gqin,
                   const float* __restrict__ gmin,
                   const float* __restrict__ btin,
                   float* __restrict__ zout,
                   float* __restrict__ gsout,
                   float* __restrict__ gqout)
{
    constexpr int PC  = (STAGE == 2) ? 64 : 16;
    constexpr int ZST = (STAGE == 2) ? 5120 : 1280;
    constexpr int OST = PC * 20;

    __shared__ __align__(16) float featS[64 * 40];
    __shared__ __align__(16) float wS[10 * 704];   // per-tv padded to 44
    __shared__ __align__(16) float mS[64 * 401];
    __shared__ __align__(16) float leftS[64 * 20];

    const int tid = threadIdx.x;
    const int bid = blockIdx.x;
    const int p   = (STAGE == 2) ? (bid & 63) : (bid & 15);
    const int bc  = (STAGE == 2) ? (bid >> 6) : (bid >> 4);
    const int b0  = bc * 64;

    const int tv = tid & 15;   // 25 uv each
    const int tb = tid >> 4;   // 0..31 ; b = tb, tb+32
    const int mb = tid >> 2;   // matvec (tid<256): 0..63
    const int mh = tid & 3;

    for (int idx = tid; idx < 64 * 20; idx += 512) leftS[idx] = VB;

    #pragma unroll 1
    for (int n = 0; n < 4; ++n) {
        int hh, ww;
        if (STAGE == 2) {
            hh = (p >> 5) * 8 + ((p >> 1) & 7);
            ww = ((p >> 4) & 1) * 8 + (p & 1) * 4 + n;
        } else {
            hh = (p >> 3) * 4 + (p & 3);
            ww = ((p >> 2) & 1) * 4 + n;
        }
        __syncthreads();
        // stage feat (affine applied, both [z, 1-z] halves stored)
        for (int idx = tid; idx < 64 * 20; idx += 512) {
            int bl = idx / 20;
            int d  = idx - bl * 20;
            int src = (STAGE == 2) ? (d * 256 + hh * 16 + ww)
                                   : (d * 64 + hh * 8 + ww);
            int ch = src / 20;
            float sc, sh;
            if (STAGE == 2) {
                sc = scd[ch]; sh = shd[ch];
            } else {
                float mean = gsin[ch] * (1.f / 2560.f);
                float var  = gqin[ch] * (1.f / 2560.f) - mean * mean;
                float rstd = rsqrtf(var + 1e-5f);
                sc = gmin[ch] * rstd;
                sh = btin[ch] - mean * sc;
            }
            float val = zin[(size_t)(b0 + bl) * ZST + src] * sc + sh;
            featS[bl * 40 + d]      = val;
            featS[bl * 40 + 20 + d] = 1.f - val;
        }
        const float* wpn = cores + (size_t)(p * 4 + n) * 16000;

        float acc0[25], acc1[25];
        #pragma unroll
        for (int j = 0; j < 25; ++j) { acc0[j] = 0.f; acc1[j] = 0.f; }

        #pragma unroll 1
        for (int ft = 0; ft < 4; ++ft) {
            __syncthreads();
            for (int idx = tid; idx < 4000; idx += 512) {
                int fi = idx / 400;
                int c  = idx - fi * 400;
                int u  = c / 20;
                int vv = c - u * 20;
                int tw = c / 25;
                int jj = c - tw * 25;
                wS[fi * 704 + tw * 44 + jj] =
                    wpn[(u * 40 + ft * 10 + fi) * 20 + vv];
            }
            __syncthreads();
            #pragma unroll
            for (int fi = 0; fi < 10; ++fi) {
                const int f = ft * 10 + fi;
                float a0 = featS[tb * 40 + f];
                float a1 = featS[(tb + 32) * 40 + f];
                float wv[25];
                #pragma unroll
                for (int g = 0; g < 6; ++g) {
                    float4 t = *reinterpret_cast<const float4*>(
                        &wS[fi * 704 + tv * 44 + 4 * g]);
                    wv[4*g+0] = t.x; wv[4*g+1] = t.y;
                    wv[4*g+2] = t.z; wv[4*g+3] = t.w;
                }
                wv[24] = wS[fi * 704 + tv * 44 + 24];
                #pragma unroll
                for (int j = 0; j < 25; ++j) {
                    acc0[j] += a0 * wv[j];
                    acc1[j] += a1 * wv[j];
                }
            }
        }
        #pragma unroll
        for (int j = 0; j < 25; ++j) {
            mS[tb * 401 + tv * 25 + j]        = acc0[j];
            mS[(tb + 32) * 401 + tv * 25 + j] = acc1[j];
        }
        __syncthreads();
        float lacc[5];
        if (tid < 256) {
            #pragma unroll
            for (int j = 0; j < 5; ++j) lacc[j] = 0.f;
            #pragma unroll
            for (int u = 0; u < 20; ++u) {
                float lv = leftS[mb * 20 + u];
                #pragma unroll
                for (int j = 0; j < 5; ++j)
                    lacc[j] += lv * mS[mb * 401 + u * 20 + mh * 5 + j];
            }
        }
        __syncthreads();
        if (tid < 256) {
            #pragma unroll
            for (int j = 0; j < 5; ++j) leftS[mb * 20 + mh * 5 + j] = lacc[j];
        }
    }
    __syncthreads();

    for (int idx = tid; idx < 400; idx += 512) {
        int u = idx / 20;
        int o = idx - u * 20;
        const float* lb = label + (size_t)((p * 20 + u) * 20 + o) * 20;
        float s = 0.f;
        #pragma unroll
        for (int vv = 0; vv < 20; ++vv) s += lb[vv];
        wS[idx] = s * VB;
    }
    __syncthreads();
    if (tid < 256) {
        float yv[5];
        #pragma unroll
        for (int j = 0; j < 5; ++j) yv[j] = 0.f;
        #pragma unroll
        for (int u = 0; u < 20; ++u) {
            float lv = leftS[mb * 20 + u];
            #pragma unroll
            for (int j = 0; j < 5; ++j) yv[j] += lv * wS[u * 20 + mh * 5 + j];
        }
        float s = 0.f, s2 = 0.f;
        #pragma unroll
        for (int j = 0; j < 5; ++j) {
            zout[(size_t)(b0 + mb) * OST + p * 20 + mh * 5 + j] = yv[j];
            s += yv[j]; s2 += yv[j] * yv[j];
        }
        #pragma unroll
        for (int off = 32; off > 0; off >>= 1) {
            s  += __shfl_down(s, off);
            s2 += __shfl_down(s2, off);
        }
        if ((tid & 63) == 0) {
            atomicAdd(&gsout[p], s);
            atomicAdd(&gqout[p], s2);
        }
    }
}

// ---------------------------------------------------------------------------
// Final MPS over 16 sites (channels = 20). One block per batch element.
// ---------------------------------------------------------------------------
__global__ __launch_bounds__(512, 2)
void final_kernel(const float* __restrict__ z3,
                  const float* __restrict__ coresF,
                  const float* __restrict__ labelF,
                  const float* __restrict__ g3,
                  const float* __restrict__ b3,
                  const float* __restrict__ gsum3,
                  const float* __restrict__ gsq3,
                  float* __restrict__ out)
{
    __shared__ float fS[40];
    __shared__ float mS[400];
    __shared__ float leftS[20];
    __shared__ float lvS[200];
    __shared__ float scS[16], shS[16];

    const int b   = blockIdx.x;
    const int tid = threadIdx.x;

    if (tid < 16) {
        float mean = gsum3[tid] * (1.f / 2560.f);
        float var  = gsq3[tid] * (1.f / 2560.f) - mean * mean;
        float rstd = rsqrtf(var + 1e-5f);
        float sc   = g3[tid] * rstd;
        scS[tid] = sc;
        shS[tid] = b3[tid] - mean * sc;
    }
    if (tid < 20) leftS[tid] = VB;
    __syncthreads();

    #pragma unroll 1
    for (int n = 0; n < 16; ++n) {
        if (tid < 20) {
            float raw = z3[(size_t)b * 320 + n * 20 + tid];
            float val = raw * scS[n] + shS[n];
            fS[tid]      = val;
            fS[20 + tid] = 1.f - val;
        }
        __syncthreads();
        if (tid < 400) {
            int u  = tid / 20;
            int vv = tid - u * 20;
            const float* wb = coresF + ((size_t)(n * 20 + u) * 40) * 20 + vv;
            float acc = 0.f;
            #pragma unroll
            for (int f = 0; f < 40; ++f) acc += fS[f] * wb[f * 20];
            mS[tid] = acc;
        }
        __syncthreads();
        float tmp = 0.f;
        if (tid < 20) {
            #pragma unroll
            for (int u = 0; u < 20; ++u) tmp += leftS[u] * mS[u * 20 + tid];
        }
        __syncthreads();
        if (tid < 20) leftS[tid] = tmp;
        __syncthreads();
    }
    if (tid < 200) {
        int u = tid / 10;
        int o = tid - u * 10;
        const float* lb = labelF + (size_t)(u * 10 + o) * 20;
        float s = 0.f;
        #pragma unroll
        for (int vv = 0; vv < 20; ++vv) s += lb[vv];
        lvS[tid] = s * VB;
    }
    __syncthreads();
    if (tid < 10) {
        float s = 0.f;
        #pragma unroll
        for (int u = 0; u < 20; ++u) s += leftS[u] * lvS[u * 10 + tid];
        out[b * 10 + tid] = s;
    }
}

// ---------------------------------------------------------------------------
extern "C" void kernel_launch(void* const* d_in, const int* in_sizes, int n_in,
                              void* d_out, int out_size, void* d_ws, size_t ws_size,
                              hipStream_t stream)
{
    const float* x      = (const float*)d_in[0];
    const float* cores1 = (const float*)d_in[1];
    const float* label1 = (const float*)d_in[2];
    const float* g1     = (const float*)d_in[3];
    const float* b1     = (const float*)d_in[4];
    const float* cores2 = (const float*)d_in[5];
    const float* label2 = (const float*)d_in[6];
    const float* g2     = (const float*)d_in[7];
    const float* b2     = (const float*)d_in[8];
    const float* cores3 = (const float*)d_in[9];
    const float* label3 = (const float*)d_in[10];
    const float* g3     = (const float*)d_in[11];
    const float* b3     = (const float*)d_in[12];
    const float* coresF = (const float*)d_in[13];
    const float* labelF = (const float*)d_in[14];

    float* ws  = (float*)d_ws;
    float* z1  = ws;                 // 128*256*20 = 655360
    float* z2  = ws + 655360;        // 128*64*20  = 163840
    float* z3  = ws + 819200;        // 128*16*20  = 40960
    float* sc1 = ws + 860160;        // 256
    float* sh1 = ws + 860416;        // 256
    float* gs2 = ws + 860672;        // 64
    float* gq2 = ws + 860736;        // 64
    float* gs3 = ws + 860800;        // 16
    float* gq3 = ws + 860816;        // 16

    // zero the atomic BN-sum region (gs2..gq3 = 160 floats)
    hipMemsetAsync(gs2, 0, 160 * sizeof(float), stream);

    stage1_kernel<<<256, 512, 0, stream>>>(x, cores1, label1, g1, b1,
                                           z1, sc1, sh1);
    stageN_kernel<2><<<128, 512, 0, stream>>>(z1, cores2, label2, sc1, sh1,
                                              nullptr, nullptr, nullptr, nullptr,
                                              z2, gs2, gq2);
    stageN_kernel<3><<<32, 512, 0, stream>>>(z2, cores3, label3, nullptr, nullptr,
                                             gs2, gq2, g2, b2,
                                             z3, gs3, gq3);
    final_kernel<<<128, 512, 0, stream>>>(z3, coresF, labelF, g3, b3,
                                          gs3, gq3, (float*)d_out);
}

// Round 3
// 375.966 us; speedup vs baseline: 1.3910x; 1.3910x over previous
//
#include <hip/hip_runtime.h>

#define VB 0.22360679774997896f  // 20^-0.5

typedef __attribute__((ext_vector_type(8))) short short8;
typedef __attribute__((ext_vector_type(4))) float f32x4;

__device__ __forceinline__ unsigned short f2bf(float f) {
    unsigned u = __float_as_uint(f);
    unsigned r = (u + 0x7fffu + ((u >> 16) & 1u)) >> 16;
    return (unsigned short)r;
}
__device__ __forceinline__ float bf2f(unsigned short h) {
    return __uint_as_float(((unsigned)h) << 16);
}
__device__ __forceinline__ void splitbf(float f, unsigned short* hi, unsigned short* lo) {
    unsigned short h = f2bf(f);
    *hi = h;
    *lo = f2bf(f - bf2f(h));
}

// ---------------------------------------------------------------------------
// Stage 1 (split-bf16 MFMA): 256 blocks (1 per patch), 512 threads (8 waves).
// Per site n: GEMM feat[128x96] @ W[96x400] via mfma_f32_16x16x32_bf16 with
// hi/lo decomposition (3 MFMAs: hh + hl + lh) -> fp32-class accuracy.
// N split into 5 u-chunks of 80 cols (chunk = contiguous 30.72 KB of cores1).
// W reg-staged one chunk ahead. Chain matvec fused per chunk. BN folded into
// (sc1, sh1) consumed by stage 2.
// ---------------------------------------------------------------------------
__global__ __launch_bounds__(512, 1)
void stage1_kernel(const float* __restrict__ x,
                   const float* __restrict__ cores1,
                   const float* __restrict__ label1,
                   const float* __restrict__ g1,
                   const float* __restrict__ b1,
                   float* __restrict__ z1,
                   float* __restrict__ sc1,
                   float* __restrict__ sh1)
{
    __shared__ __align__(16) float MchunkS[128 * 84];           // 43008 B (aliases xS)
    __shared__ __align__(16) unsigned short featFragHi[12288];  // 24576 B
    __shared__ __align__(16) unsigned short featFragLo[12288];  // 24576 B
    __shared__ __align__(16) unsigned short wfragHi[7680];      // 15360 B
    __shared__ __align__(16) unsigned short wfragLo[7680];      // 15360 B
    __shared__ __align__(16) float leftS[128 * 20];             // 10240 B
    __shared__ float redS[2];
    float* xS = MchunkS;  // [128][49] = 25088 B, lifetime barrier-separated

    const int tid = threadIdx.x;
    const int p   = blockIdx.x;

    if (tid == 0) { redS[0] = 0.f; redS[1] = 0.f; }
    for (int idx = tid; idx < 128 * 20; idx += 512) leftS[idx] = VB;

    const float* wsite = cores1 + (size_t)p * 153600;  // 4 sites * 38400

    // ---- W reg-prefetch buffers (chunk = 1920 float4) ----
    float4 wrA[4], wrB[4];
    #pragma unroll
    for (int k = 0; k < 4; ++k) {
        int idx4 = tid + k * 512;
        if (idx4 < 1920) wrA[k] = *(const float4*)(wsite + idx4 * 4);
    }

    float lacc[5];

    #pragma unroll 1
    for (int pb = 0; pb < 20; ++pb) {
        const int n  = pb / 5;
        const int uc = pb - n * 5;

        if (uc == 0) {
            // ---- site head ----
            if (n > 0) {
                __syncthreads();  // chain reads of leftS/Mchunk done
                const int bb = tid >> 2, mh = tid & 3;
                #pragma unroll
                for (int j = 0; j < 5; ++j) leftS[bb * 20 + mh * 5 + j] = lacc[j];
            }
            #pragma unroll
            for (int j = 0; j < 5; ++j) lacc[j] = 0.f;

            const int hh = (p >> 7) * 16 + ((p >> 2) & 15);
            const int ww = ((p >> 6) & 1) * 16 + (p & 3) * 4 + n;
            __syncthreads();  // leftS written / xS (Mchunk) free
            for (int idx = tid; idx < 6144; idx += 512) {
                int bb = idx / 48, c = idx - bb * 48;
                xS[bb * 49 + c] = x[((size_t)(bb * 48 + c) << 10) + hh * 32 + ww];
            }
            __syncthreads();  // xS ready
            // build A-frags: [((mt*3+ks)*64+l)*8+j], k = (l>>4)*8+j within K32
            for (int g = tid; g < 1536; g += 512) {
                int mtks = g >> 6, l = g & 63;
                int mt = mtks / 3, ks = mtks - mt * 3;
                int row = mt * 16 + (l & 15);
                int f0  = ks * 32 + ((l >> 4) << 3);
                unsigned short h[8], lo[8];
                if (f0 < 48) {
                    #pragma unroll
                    for (int j = 0; j < 8; ++j)
                        splitbf(xS[row * 49 + f0 + j], &h[j], &lo[j]);
                } else {
                    #pragma unroll
                    for (int j = 0; j < 8; ++j)
                        splitbf(1.f - xS[row * 49 + f0 - 48 + j], &h[j], &lo[j]);
                }
                uint4 w4;
                w4.x = h[0] | ((unsigned)h[1] << 16);
                w4.y = h[2] | ((unsigned)h[3] << 16);
                w4.z = h[4] | ((unsigned)h[5] << 16);
                w4.w = h[6] | ((unsigned)h[7] << 16);
                *(uint4*)&featFragHi[g * 8] = w4;
                w4.x = lo[0] | ((unsigned)lo[1] << 16);
                w4.y = lo[2] | ((unsigned)lo[3] << 16);
                w4.z = lo[4] | ((unsigned)lo[5] << 16);
                w4.w = lo[6] | ((unsigned)lo[7] << 16);
                *(uint4*)&featFragLo[g * 8] = w4;
            }
        }

        // ---- frag-build for chunk pb from W regs; prefetch chunk pb+1 ----
        const float4* wr = (pb & 1) ? wrB : wrA;
        #pragma unroll
        for (int k = 0; k < 4; ++k) {
            int idx4 = tid + k * 512;
            if (idx4 < 1920) {
                float vals[4] = {wr[k].x, wr[k].y, wr[k].z, wr[k].w};
                #pragma unroll
                for (int t = 0; t < 4; ++t) {
                    int e = idx4 * 4 + t;
                    int v = e % 20;
                    int r = e / 20;
                    int f = r % 96;
                    int ul = r / 96;
                    int c = ul * 20 + v;
                    int addr = ((((f >> 5) * 5 + (c >> 4)) << 6) +
                                (((f >> 3) & 3) << 4) + (c & 15)) * 8 + (f & 7);
                    unsigned short h, lo;
                    splitbf(vals[t], &h, &lo);
                    wfragHi[addr] = h;
                    wfragLo[addr] = lo;
                }
            }
        }
        if (pb < 19) {
            const int pn = pb + 1;
            const int n2 = pn / 5, uc2 = pn - n2 * 5;
            const float* wb2 = wsite + (size_t)n2 * 38400 + uc2 * 7680;
            float4* wrN = (pb & 1) ? wrA : wrB;
            #pragma unroll
            for (int k = 0; k < 4; ++k) {
                int idx4 = tid + k * 512;
                if (idx4 < 1920) wrN[k] = *(const float4*)(wb2 + idx4 * 4);
            }
        }
        __syncthreads();  // wfrag (and featFrag, xS reads) ready

        // ---- GEMM: wave w owns M-tile w (rows 16w..16w+15), 5 N-tiles ----
        {
            const int wv = tid >> 6, lane = tid & 63;
            f32x4 acc[5];
            #pragma unroll
            for (int nt = 0; nt < 5; ++nt) acc[nt] = (f32x4){0.f, 0.f, 0.f, 0.f};
            #pragma unroll
            for (int ks = 0; ks < 3; ++ks) {
                short8 ah = *(const short8*)&featFragHi[((wv * 3 + ks) * 64 + lane) * 8];
                short8 al = *(const short8*)&featFragLo[((wv * 3 + ks) * 64 + lane) * 8];
                #pragma unroll
                for (int nt = 0; nt < 5; ++nt) {
                    short8 bh = *(const short8*)&wfragHi[((ks * 5 + nt) * 64 + lane) * 8];
                    short8 bl = *(const short8*)&wfragLo[((ks * 5 + nt) * 64 + lane) * 8];
                    acc[nt] = __builtin_amdgcn_mfma_f32_16x16x32_bf16(ah, bh, acc[nt], 0, 0, 0);
                    acc[nt] = __builtin_amdgcn_mfma_f32_16x16x32_bf16(ah, bl, acc[nt], 0, 0, 0);
                    acc[nt] = __builtin_amdgcn_mfma_f32_16x16x32_bf16(al, bh, acc[nt], 0, 0, 0);
                }
            }
            // D layout: col = lane&15, row = (lane>>4)*4 + r  [m89-verified]
            const int rowg = lane >> 4, colg = lane & 15;
            #pragma unroll
            for (int nt = 0; nt < 5; ++nt) {
                #pragma unroll
                for (int r = 0; r < 4; ++r)
                    MchunkS[(wv * 16 + rowg * 4 + r) * 84 + nt * 16 + colg] = acc[nt][r];
            }
        }
        __syncthreads();  // Mchunk ready; wfrag consumed

        // ---- partial chain: lacc[v] += sum_{ul} left[u]*M[u][v] ----
        {
            const int bb = tid >> 2, mh = tid & 3;
            #pragma unroll
            for (int ul = 0; ul < 4; ++ul) {
                float lv = leftS[bb * 20 + uc * 4 + ul];
                #pragma unroll
                for (int j = 0; j < 5; ++j)
                    lacc[j] += lv * MchunkS[bb * 84 + ul * 20 + mh * 5 + j];
            }
        }
    }

    // ---- epilogue: label contraction + z1 + BN fold ----
    __syncthreads();
    {
        const int bb = tid >> 2, mh = tid & 3;
        #pragma unroll
        for (int j = 0; j < 5; ++j) leftS[bb * 20 + mh * 5 + j] = lacc[j];
    }
    __syncthreads();
    float* labv = MchunkS;  // reuse as [20u][20o]
    for (int idx = tid; idx < 400; idx += 512) {
        int u = idx / 20, o = idx - u * 20;
        const float* lb = label1 + (size_t)((p * 20 + u) * 20 + o) * 20;
        float s = 0.f;
        #pragma unroll
        for (int vv = 0; vv < 20; ++vv) s += lb[vv];
        labv[idx] = s * VB;
    }
    __syncthreads();
    {
        const int mb = tid >> 2, mh = tid & 3;
        float yv[5];
        #pragma unroll
        for (int j = 0; j < 5; ++j) yv[j] = 0.f;
        #pragma unroll
        for (int u = 0; u < 20; ++u) {
            float lv = leftS[mb * 20 + u];
            #pragma unroll
            for (int j = 0; j < 5; ++j) yv[j] += lv * labv[u * 20 + mh * 5 + j];
        }
        float s = 0.f, s2 = 0.f;
        #pragma unroll
        for (int j = 0; j < 5; ++j) {
            z1[(size_t)mb * 5120 + p * 20 + mh * 5 + j] = yv[j];
            s += yv[j]; s2 += yv[j] * yv[j];
        }
        #pragma unroll
        for (int off = 32; off > 0; off >>= 1) {
            s  += __shfl_down(s, off);
            s2 += __shfl_down(s2, off);
        }
        if ((tid & 63) == 0) { atomicAdd(&redS[0], s); atomicAdd(&redS[1], s2); }
    }
    __syncthreads();
    if (tid == 0) {
        float mean = redS[0] * (1.f / 2560.f);
        float var  = redS[1] * (1.f / 2560.f) - mean * mean;
        float rstd = rsqrtf(var + 1e-5f);
        float sc   = g1[p] * rstd;
        sc1[p] = sc;
        sh1[p] = b1[p] - mean * sc;
    }
}

// ---------------------------------------------------------------------------
// Stages 2 & 3 (unchanged, verified round-1 code)
// ---------------------------------------------------------------------------
template <int STAGE>
__global__ __launch_bounds__(512, 2)
void stageN_kernel(const float* __restrict__ zin,
                   const float* __restrict__ cores,
                   const float* __restrict__ label,
                   const float* __restrict__ scd,
                   const float* __restrict__ shd,
                   const float* __restrict__ gsin,
                   const float* __restrict__ gqin,
                   const float* __restrict__ gmin,
                   const float* __restrict__ btin,
                   float* __restrict__ zout,
                   float* __restrict__ gsout,
                   float* __restrict__ gqout)
{
    constexpr int PC  = (STAGE == 2) ? 64 : 16;
    constexpr int ZST = (STAGE == 2) ? 5120 : 1280;
    constexpr int OST = PC * 20;

    __shared__ __align__(16) float featS[64 * 40];
    __shared__ __align__(16) float wS[10 * 704];
    __shared__ __align__(16) float mS[64 * 401];
    __shared__ __align__(16) float leftS[64 * 20];

    const int tid = threadIdx.x;
    const int bid = blockIdx.x;
    const int p   = (STAGE == 2) ? (bid & 63) : (bid & 15);
    const int bc  = (STAGE == 2) ? (bid >> 6) : (bid >> 4);
    const int b0  = bc * 64;

    const int tv = tid & 15;
    const int tb = tid >> 4;
    const int mb = tid >> 2;
    const int mh = tid & 3;

    for (int idx = tid; idx < 64 * 20; idx += 512) leftS[idx] = VB;

    #pragma unroll 1
    for (int n = 0; n < 4; ++n) {
        int hh, ww;
        if (STAGE == 2) {
            hh = (p >> 5) * 8 + ((p >> 1) & 7);
            ww = ((p >> 4) & 1) * 8 + (p & 1) * 4 + n;
        } else {
            hh = (p >> 3) * 4 + (p & 3);
            ww = ((p >> 2) & 1) * 4 + n;
        }
        __syncthreads();
        for (int idx = tid; idx < 64 * 20; idx += 512) {
            int bl = idx / 20;
            int d  = idx - bl * 20;
            int src = (STAGE == 2) ? (d * 256 + hh * 16 + ww)
                                   : (d * 64 + hh * 8 + ww);
            int ch = src / 20;
            float sc, sh;
            if (STAGE == 2) {
                sc = scd[ch]; sh = shd[ch];
            } else {
                float mean = gsin[ch] * (1.f / 2560.f);
                float var  = gqin[ch] * (1.f / 2560.f) - mean * mean;
                float rstd = rsqrtf(var + 1e-5f);
                sc = gmin[ch] * rstd;
                sh = btin[ch] - mean * sc;
            }
            float val = zin[(size_t)(b0 + bl) * ZST + src] * sc + sh;
            featS[bl * 40 + d]      = val;
            featS[bl * 40 + 20 + d] = 1.f - val;
        }
        const float* wpn = cores + (size_t)(p * 4 + n) * 16000;

        float acc0[25], acc1[25];
        #pragma unroll
        for (int j = 0; j < 25; ++j) { acc0[j] = 0.f; acc1[j] = 0.f; }

        #pragma unroll 1
        for (int ft = 0; ft < 4; ++ft) {
            __syncthreads();
            for (int idx = tid; idx < 4000; idx += 512) {
                int fi = idx / 400;
                int c  = idx - fi * 400;
                int u  = c / 20;
                int vv = c - u * 20;
                int tw = c / 25;
                int jj = c - tw * 25;
                wS[fi * 704 + tw * 44 + jj] =
                    wpn[(u * 40 + ft * 10 + fi) * 20 + vv];
            }
            __syncthreads();
            #pragma unroll
            for (int fi = 0; fi < 10; ++fi) {
                const int f = ft * 10 + fi;
                float a0 = featS[tb * 40 + f];
                float a1 = featS[(tb + 32) * 40 + f];
                float wv[25];
                #pragma unroll
                for (int g = 0; g < 6; ++g) {
                    float4 t = *reinterpret_cast<const float4*>(
                        &wS[fi * 704 + tv * 44 + 4 * g]);
                    wv[4*g+0] = t.x; wv[4*g+1] = t.y;
                    wv[4*g+2] = t.z; wv[4*g+3] = t.w;
                }
                wv[24] = wS[fi * 704 + tv * 44 + 24];
                #pragma unroll
                for (int j = 0; j < 25; ++j) {
                    acc0[j] += a0 * wv[j];
                    acc1[j] += a1 * wv[j];
                }
            }
        }
        #pragma unroll
        for (int j = 0; j < 25; ++j) {
            mS[tb * 401 + tv * 25 + j]        = acc0[j];
            mS[(tb + 32) * 401 + tv * 25 + j] = acc1[j];
        }
        __syncthreads();
        float lacc[5];
        if (tid < 256) {
            #pragma unroll
            for (int j = 0; j < 5; ++j) lacc[j] = 0.f;
            #pragma unroll
            for (int u = 0; u < 20; ++u) {
                float lv = leftS[mb * 20 + u];
                #pragma unroll
                for (int j = 0; j < 5; ++j)
                    lacc[j] += lv * mS[mb * 401 + u * 20 + mh * 5 + j];
            }
        }
        __syncthreads();
        if (tid < 256) {
            #pragma unroll
            for (int j = 0; j < 5; ++j) leftS[mb * 20 + mh * 5 + j] = lacc[j];
        }
    }
    __syncthreads();

    for (int idx = tid; idx < 400; idx += 512) {
        int u = idx / 20;
        int o = idx - u * 20;
        const float* lb = label + (size_t)((p * 20 + u) * 20 + o) * 20;
        float s = 0.f;
        #pragma unroll
        for (int vv = 0; vv < 20; ++vv) s += lb[vv];
        wS[idx] = s * VB;
    }
    __syncthreads();
    if (tid < 256) {
        float yv[5];
        #pragma unroll
        for (int j = 0; j < 5; ++j) yv[j] = 0.f;
        #pragma unroll
        for (int u = 0; u < 20; ++u) {
            float lv = leftS[mb * 20 + u];
            #pragma unroll
            for (int j = 0; j < 5; ++j) yv[j] += lv * wS[u * 20 + mh * 5 + j];
        }
        float s = 0.f, s2 = 0.f;
        #pragma unroll
        for (int j = 0; j < 5; ++j) {
            zout[(size_t)(b0 + mb) * OST + p * 20 + mh * 5 + j] = yv[j];
            s += yv[j]; s2 += yv[j] * yv[j];
        }
        #pragma unroll
        for (int off = 32; off > 0; off >>= 1) {
            s  += __shfl_down(s, off);
            s2 += __shfl_down(s2, off);
        }
        if ((tid & 63) == 0) {
            atomicAdd(&gsout[p], s);
            atomicAdd(&gqout[p], s2);
        }
    }
}

// ---------------------------------------------------------------------------
// Final MPS (unchanged)
// ---------------------------------------------------------------------------
__global__ __launch_bounds__(512, 2)
void final_kernel(const float* __restrict__ z3,
                  const float* __restrict__ coresF,
                  const float* __restrict__ labelF,
                  const float* __restrict__ g3,
                  const float* __restrict__ b3,
                  const float* __restrict__ gsum3,
                  const float* __restrict__ gsq3,
                  float* __restrict__ out)
{
    __shared__ float fS[40];
    __shared__ float mS[400];
    __shared__ float leftS[20];
    __shared__ float lvS[200];
    __shared__ float scS[16], shS[16];

    const int b   = blockIdx.x;
    const int tid = threadIdx.x;

    if (tid < 16) {
        float mean = gsum3[tid] * (1.f / 2560.f);
        float var  = gsq3[tid] * (1.f / 2560.f) - mean * mean;
        float rstd = rsqrtf(var + 1e-5f);
        float sc   = g3[tid] * rstd;
        scS[tid] = sc;
        shS[tid] = b3[tid] - mean * sc;
    }
    if (tid < 20) leftS[tid] = VB;
    __syncthreads();

    #pragma unroll 1
    for (int n = 0; n < 16; ++n) {
        if (tid < 20) {
            float raw = z3[(size_t)b * 320 + n * 20 + tid];
            float val = raw * scS[n] + shS[n];
            fS[tid]      = val;
            fS[20 + tid] = 1.f - val;
        }
        __syncthreads();
        if (tid < 400) {
            int u  = tid / 20;
            int vv = tid - u * 20;
            const float* wb = coresF + ((size_t)(n * 20 + u) * 40) * 20 + vv;
            float acc = 0.f;
            #pragma unroll
            for (int f = 0; f < 40; ++f) acc += fS[f] * wb[f * 20];
            mS[tid] = acc;
        }
        __syncthreads();
        float tmp = 0.f;
        if (tid < 20) {
            #pragma unroll
            for (int u = 0; u < 20; ++u) tmp += leftS[u] * mS[u * 20 + tid];
        }
        __syncthreads();
        if (tid < 20) leftS[tid] = tmp;
        __syncthreads();
    }
    if (tid < 200) {
        int u = tid / 10;
        int o = tid - u * 10;
        const float* lb = labelF + (size_t)(u * 10 + o) * 20;
        float s = 0.f;
        #pragma unroll
        for (int vv = 0; vv < 20; ++vv) s += lb[vv];
        lvS[tid] = s * VB;
    }
    __syncthreads();
    if (tid < 10) {
        float s = 0.f;
        #pragma unroll
        for (int u = 0; u < 20; ++u) s += leftS[u] * lvS[u * 10 + tid];
        out[b * 10 + tid] = s;
    }
}

// ---------------------------------------------------------------------------
extern "C" void kernel_launch(void* const* d_in, const int* in_sizes, int n_in,
                              void* d_out, int out_size, void* d_ws, size_t ws_size,
                              hipStream_t stream)
{
    const float* x      = (const float*)d_in[0];
    const float* cores1 = (const float*)d_in[1];
    const float* label1 = (const float*)d_in[2];
    const float* g1     = (const float*)d_in[3];
    const float* b1     = (const float*)d_in[4];
    const float* cores2 = (const float*)d_in[5];
    const float* label2 = (const float*)d_in[6];
    const float* g2     = (const float*)d_in[7];
    const float* b2     = (const float*)d_in[8];
    const float* cores3 = (const float*)d_in[9];
    const float* label3 = (const float*)d_in[10];
    const float* g3     = (const float*)d_in[11];
    const float* b3     = (const float*)d_in[12];
    const float* coresF = (const float*)d_in[13];
    const float* labelF = (const float*)d_in[14];

    float* ws  = (float*)d_ws;
    float* z1  = ws;                 // 128*256*20 = 655360
    float* z2  = ws + 655360;        // 128*64*20  = 163840
    float* z3  = ws + 819200;        // 128*16*20  = 40960
    float* sc1 = ws + 860160;        // 256
    float* sh1 = ws + 860416;        // 256
    float* gs2 = ws + 860672;        // 64
    float* gq2 = ws + 860736;        // 64
    float* gs3 = ws + 860800;        // 16
    float* gq3 = ws + 860816;        // 16

    hipMemsetAsync(gs2, 0, 160 * sizeof(float), stream);

    stage1_kernel<<<256, 512, 0, stream>>>(x, cores1, label1, g1, b1,
                                           z1, sc1, sh1);
    stageN_kernel<2><<<128, 512, 0, stream>>>(z1, cores2, label2, sc1, sh1,
                                              nullptr, nullptr, nullptr, nullptr,
                                              z2, gs2, gq2);
    stageN_kernel<3><<<32, 512, 0, stream>>>(z2, cores3, label3, nullptr, nullptr,
                                             gs2, gq2, g2, b2,
                                             z3, gs3, gq3);
    final_kernel<<<128, 512, 0, stream>>>(z3, coresF, labelF, g3, b3,
                                          gs3, gq3, (float*)d_out);
}